// Round 5
// baseline (2837.677 us; speedup 1.0000x reference)
//
#include <hip/hip_runtime.h>
#include <hip/hip_bf16.h>

#define NB   4
#define NPTS 16384
#define NC   64
#define NM   1024
#define NK   32
#define NCP  67
#define RAD2 0.25f

// workspace offsets in 4-byte units (total ~323k floats = 1.29 MB)
#define OFF_W0T     0u        // 67*128 = 8576
#define OFF_W1T     8576u     // 128*256 = 32768
#define OFF_NEWXYZ  41344u    // 12288
#define OFF_IDXBALL 53632u    // 4*1024*32 = 131072 (int)
#define OFF_CNT     184704u   // 65536 (int)
#define OFF_EMB     250240u   // 384
#define OFF_PW      250624u   // 4096
#define OFF_PE      254720u   // 68608 -> ends 323328

// output offsets (FLOAT32 elements; d_out is float*)
#define OUT_NEWXYZ 0u
#define OUT_POOLED 12288u
#define OUT_IDX    1060864u

// ---------------- transpose weights ----------------
__global__ __launch_bounds__(256) void k_prepw(const float* __restrict__ w0,
                                               const float* __restrict__ w1,
                                               float* __restrict__ w0t,
                                               float* __restrict__ w1t) {
  int t = blockIdx.x * 256 + threadIdx.x;
  if (t < 128 * NCP) { int o = t / NCP, c = t % NCP; w0t[c * 128 + o] = w0[t]; }
  if (t < 256 * 128) { int o2 = t / 128, o = t % 128; w1t[o * 256 + o2] = w1[t]; }
}

// ---------------- furthest point sampling ----------------
// one block per batch; 1024 threads, 16 points each (interleaved p = t+1024*i).
// (x,y) of all points in LDS (128 KiB); z + running min-dist in registers.
// One barrier per step (ping-ponged candidate buffers). Candidate z is carried
// through both argmax reduces so the serial chain never touches global memory.
// Distances use explicit non-FMA f32 ops, (dx*dx+dy*dy)+dz*dz order, strict->
// compare with global-index tie-break => picks bit-match numpy/jax argmax.
__global__ __launch_bounds__(1024) void k_fps(const float* __restrict__ xyz,
                                              float* __restrict__ newxyz,
                                              float* __restrict__ out) {
  const int b = blockIdx.x;
  const int t = threadIdx.x;
  const float* xb = xyz + (size_t)b * NPTS * 3;
  __shared__ float2 sxy[NPTS];     // 128 KiB
  __shared__ float c_val[2][16];
  __shared__ int   c_idx[2][16];
  __shared__ float c_z[2][16];
  float pz[16], md[16];
#pragma unroll
  for (int i = 0; i < 16; ++i) {
    int p = t + 1024 * i;
    float x = xb[p * 3 + 0];
    float y = xb[p * 3 + 1];
    float z = xb[p * 3 + 2];
    sxy[p] = make_float2(x, y);
    pz[i] = z;
    md[i] = 1e10f;
  }
  float lx = xb[0], ly = xb[1], lz = xb[2];
  if (t == 0) {
    newxyz[(size_t)b * NM * 3 + 0] = lx;
    newxyz[(size_t)b * NM * 3 + 1] = ly;
    newxyz[(size_t)b * NM * 3 + 2] = lz;
    out[OUT_NEWXYZ + (size_t)b * NM * 3 + 0] = lx;
    out[OUT_NEWXYZ + (size_t)b * NM * 3 + 1] = ly;
    out[OUT_NEWXYZ + (size_t)b * NM * 3 + 2] = lz;
    out[OUT_IDX + b * NM] = 0.0f;
  }
  __syncthreads();
  for (int s = 1; s < NM; ++s) {
    float best = -1.0f;
    int   bidx = 0;
    float bz   = 0.0f;
#pragma unroll
    for (int i = 0; i < 16; ++i) {
      int p = t + 1024 * i;
      float2 xy = sxy[p];
      float dx = __fsub_rn(xy.x, lx);
      float dy = __fsub_rn(xy.y, ly);
      float dz = __fsub_rn(pz[i], lz);
      float d2 = __fadd_rn(__fadd_rn(__fmul_rn(dx, dx), __fmul_rn(dy, dy)),
                           __fmul_rn(dz, dz));
      float m0 = fminf(md[i], d2);
      md[i] = m0;
      bool gt = m0 > best;               // i ascending => p ascending: first-max kept
      best = gt ? m0 : best;
      bidx = gt ? p : bidx;
      bz   = gt ? pz[i] : bz;
    }
    // wave argmax with global-index tie-break (first index wins), carrying z
#pragma unroll
    for (int off = 1; off < 64; off <<= 1) {
      float ov = __shfl_xor(best, off);
      int   oi = __shfl_xor(bidx, off);
      float oz = __shfl_xor(bz, off);
      bool tk = ov > best || (ov == best && oi < bidx);
      best = tk ? ov : best;
      bidx = tk ? oi : bidx;
      bz   = tk ? oz : bz;
    }
    const int pp = s & 1;
    if ((t & 63) == 0) {
      c_val[pp][t >> 6] = best;
      c_idx[pp][t >> 6] = bidx;
      c_z[pp][t >> 6]   = bz;
    }
    __syncthreads();
    // cross-wave fold: lane (t&15) loads candidate (t&15); 4-stage xor
    // butterfly gives every lane the global argmax of the 16 candidates.
    float v  = c_val[pp][t & 15];
    int   vi = c_idx[pp][t & 15];
    float vz = c_z[pp][t & 15];
#pragma unroll
    for (int off = 1; off < 16; off <<= 1) {
      float ov = __shfl_xor(v, off);
      int   oi = __shfl_xor(vi, off);
      float oz = __shfl_xor(vz, off);
      bool tk = ov > v || (ov == v && oi < vi);
      v  = tk ? ov : v;
      vi = tk ? oi : vi;
      vz = tk ? oz : vz;
    }
    const int bi = vi;
    float2 cxy = sxy[bi];   // broadcast LDS read (same addr across lanes)
    lx = cxy.x; ly = cxy.y; lz = vz;
    if (t == 0) {
      newxyz[((size_t)b * NM + s) * 3 + 0] = lx;
      newxyz[((size_t)b * NM + s) * 3 + 1] = ly;
      newxyz[((size_t)b * NM + s) * 3 + 2] = lz;
      out[OUT_NEWXYZ + ((size_t)b * NM + s) * 3 + 0] = lx;
      out[OUT_NEWXYZ + ((size_t)b * NM + s) * 3 + 1] = ly;
      out[OUT_NEWXYZ + ((size_t)b * NM + s) * 3 + 2] = lz;
      out[OUT_IDX + b * NM + s] = (float)bi;
    }
  }
}

// ---------------- ball query: first NK indices with d2<=r2, pad with first ----
// one wave per (b,m); also histogram counts + xyz partial sums for emb.
__global__ __launch_bounds__(256) void k_ball(const float* __restrict__ xyz,
                                              const float* __restrict__ newxyz,
                                              int* __restrict__ idxball,
                                              int* __restrict__ cnt,
                                              float* __restrict__ emb) {
  __shared__ int s_idx[4][NK];
  const int lane = threadIdx.x & 63, wid = threadIdx.x >> 6;
  const int gid = blockIdx.x * 4 + wid; // (b,m)
  const int b = gid >> 10;
  const float* xb = xyz + (size_t)b * NPTS * 3;
  const float cx = newxyz[gid * 3 + 0];
  const float cy = newxyz[gid * 3 + 1];
  const float cz = newxyz[gid * 3 + 2];
  int total = 0;
  for (int base = 0; base < NPTS && total < NK; base += 64) {
    int n = base + lane;
    float dx = __fsub_rn(xb[n * 3 + 0], cx);
    float dy = __fsub_rn(xb[n * 3 + 1], cy);
    float dz = __fsub_rn(xb[n * 3 + 2], cz);
    float d2 = __fadd_rn(__fadd_rn(__fmul_rn(dx, dx), __fmul_rn(dy, dy)),
                         __fmul_rn(dz, dz));
    bool hit = d2 <= RAD2;
    unsigned long long mask = __ballot(hit);
    int pos = total + (int)__popcll(mask & ((1ull << lane) - 1ull));
    if (hit && pos < NK) s_idx[wid][pos] = n;
    total += (int)__popcll(mask);
  }
  int tt = total < NK ? total : NK;
  if (lane >= tt && lane < NK) s_idx[wid][lane] = s_idx[wid][0];
  int v = 0;
  if (lane < NK) {
    v = s_idx[wid][lane];
    idxball[(size_t)gid * NK + lane] = v;
    atomicAdd(&cnt[b * NPTS + v], 1);
  }
  float sx = 0.f, sy = 0.f, sz = 0.f;
  if (lane < NK) { sx = xb[v * 3 + 0]; sy = xb[v * 3 + 1]; sz = xb[v * 3 + 2]; }
#pragma unroll
  for (int off = 1; off < 64; off <<= 1) {
    sx += __shfl_xor(sx, off);
    sy += __shfl_xor(sy, off);
    sz += __shfl_xor(sz, off);
  }
  if (lane == 0) {
    atomicAdd(&emb[b * 96 + 0], sx - 32.0f * cx);
    atomicAdd(&emb[b * 96 + 1], sy - 32.0f * cy);
    atomicAdd(&emb[b * 96 + 2], sz - 32.0f * cz);
  }
}

// ---------------- emb feature part: emb[b,3+c] = sum_n cnt[b,n]*feat[b,c,n] ----
__global__ __launch_bounds__(256) void k_embfeat(const float* __restrict__ feat,
                                                 const int* __restrict__ cnt,
                                                 float* __restrict__ emb) {
  const int c = blockIdx.x, b = blockIdx.y;
  const float* f = feat + ((size_t)b * NC + c) * NPTS;
  const int* ct = cnt + b * NPTS;
  float acc = 0.f;
  for (int n = threadIdx.x; n < NPTS; n += 256)
    acc = fmaf((float)ct[n], f[n], acc);
  __shared__ float red[4];
#pragma unroll
  for (int off = 1; off < 64; off <<= 1) acc += __shfl_xor(acc, off);
  if ((threadIdx.x & 63) == 0) red[threadIdx.x >> 6] = acc;
  __syncthreads();
  if (threadIdx.x == 0)
    emb[b * 96 + 3 + c] = red[0] + red[1] + red[2] + red[3];
}

// ---------------- pe: proj + layernorm + exact gelu ----------------
__global__ __launch_bounds__(64) void k_pe(const float* __restrict__ prompt,
                                           const float* __restrict__ projw,
                                           const float* __restrict__ projb,
                                           const float* __restrict__ lng,
                                           const float* __restrict__ lnb,
                                           float* __restrict__ pe) {
  const int m = blockIdx.x, lane = threadIdx.x;
  const float p0 = prompt[m * 2 + 0], p1 = prompt[m * 2 + 1];
  const int c1 = lane, c2 = lane + 64;
  float v1 = p0 * projw[c1 * 2 + 0] + p1 * projw[c1 * 2 + 1] + projb[c1];
  float v2 = 0.f;
  if (c2 < NCP) v2 = p0 * projw[c2 * 2 + 0] + p1 * projw[c2 * 2 + 1] + projb[c2];
  float s = v1 + ((c2 < NCP) ? v2 : 0.f);
#pragma unroll
  for (int off = 1; off < 64; off <<= 1) s += __shfl_xor(s, off);
  float mu = s * (1.0f / 67.0f);
  float d1 = v1 - mu;
  float d2v = (c2 < NCP) ? (v2 - mu) : 0.f;
  float q = d1 * d1 + d2v * d2v;
#pragma unroll
  for (int off = 1; off < 64; off <<= 1) q += __shfl_xor(q, off);
  float inv = 1.0f / sqrtf(q * (1.0f / 67.0f) + 1e-5f);
  {
    float y = d1 * inv * lng[c1] + lnb[c1];
    pe[m * NCP + c1] = 0.5f * y * (1.0f + erff(y * 0.70710678118654752f));
  }
  if (c2 < NCP) {
    float y = (v2 - mu) * inv * lng[c2] + lnb[c2];
    pe[m * NCP + c2] = 0.5f * y * (1.0f + erff(y * 0.70710678118654752f));
  }
}

// ---------------- pw: softmax(emb/32768 @ pw_w.T + pw_b) ----------------
__global__ __launch_bounds__(1024) void k_pw(const float* __restrict__ emb,
                                             const float* __restrict__ pww,
                                             const float* __restrict__ pwb,
                                             float* __restrict__ pw) {
  const int b = blockIdx.x, m = threadIdx.x;
  __shared__ float se[NCP];
  __shared__ float red[16];
  __shared__ float bcast;
  if (m < NCP) se[m] = emb[b * 96 + m] * (1.0f / 32768.0f);
  __syncthreads();
  float acc = pwb[m];
  for (int c = 0; c < NCP; ++c) acc = fmaf(se[c], pww[m * NCP + c], acc);
  float mx = acc;
#pragma unroll
  for (int off = 1; off < 64; off <<= 1) mx = fmaxf(mx, __shfl_xor(mx, off));
  if ((m & 63) == 0) red[m >> 6] = mx;
  __syncthreads();
  if (m == 0) {
    float v = red[0];
    for (int w = 1; w < 16; ++w) v = fmaxf(v, red[w]);
    bcast = v;
  }
  __syncthreads();
  float e = expf(acc - bcast);
  float ssum = e;
#pragma unroll
  for (int off = 1; off < 64; off <<= 1) ssum += __shfl_xor(ssum, off);
  if ((m & 63) == 0) red[m >> 6] = ssum;
  __syncthreads();
  if (m == 0) {
    float v = 0.f;
    for (int w = 0; w < 16; ++w) v += red[w];
    bcast = v;
  }
  __syncthreads();
  pw[b * NM + m] = e / bcast;
}

// ---------------- fused gather + pe*pw + conv0 + conv1 + maxpool ----------------
__global__ __launch_bounds__(256) void k_main(const float* __restrict__ feat,
                                              const float* __restrict__ xyz,
                                              const float* __restrict__ newxyz,
                                              const int* __restrict__ idxball,
                                              const float* __restrict__ pe,
                                              const float* __restrict__ pwbuf,
                                              const float* __restrict__ w0t,
                                              const float* __restrict__ b0,
                                              const float* __restrict__ w1t,
                                              const float* __restrict__ b1,
                                              float* __restrict__ out) {
  __shared__ __align__(16) float g[NCP * 36];
  __shared__ __align__(16) float h0[128 * 36];
  __shared__ int s_idx[NK];
  __shared__ float spe[NCP];
  const int bid = blockIdx.x;
  const int b = bid >> 10, m = bid & 1023;
  const int t = threadIdx.x;
  const float pwv = pwbuf[bid];
  if (t < NK) {
    int n = idxball[(size_t)bid * NK + t];
    n = n < 0 ? 0 : (n > NPTS - 1 ? NPTS - 1 : n); // insurance clamp
    s_idx[t] = n;
  }
  if (t < NCP) spe[t] = pe[m * NCP + t] * pwv;
  __syncthreads();
  // stage feature rows of g (gather from native (B,C,N) layout; L3-resident)
  for (int e = t; e < NK * NC; e += 256) {
    int k = e >> 6, c = e & 63;
    int n = s_idx[k];
    g[(3 + c) * 36 + k] = feat[((size_t)b * NC + c) * NPTS + n] + spe[3 + c];
  }
  // stage xyz rows of g
  if (t < 96) {
    int k = t & 31, d = t >> 5;
    int n = s_idx[k];
    float cv = newxyz[bid * 3 + d];
    g[d * 36 + k] = (xyz[((size_t)b * NPTS + n) * 3 + d] - cv) + spe[d];
  }
  __syncthreads();
  // layer0: h0[o][k] = relu(sum_c W0[o,c]*g[c,k] + b0[o])
  {
    const int o = t & 127, kb = (t >> 7) * 16;
    float acc[16];
    float bb = b0[o];
#pragma unroll
    for (int j = 0; j < 16; ++j) acc[j] = bb;
    for (int c = 0; c < NCP; ++c) {
      float w = w0t[c * 128 + o];
      const float4* gp = reinterpret_cast<const float4*>(&g[c * 36 + kb]);
#pragma unroll
      for (int qq = 0; qq < 4; ++qq) {
        float4 gv = gp[qq];
        acc[qq * 4 + 0] = fmaf(w, gv.x, acc[qq * 4 + 0]);
        acc[qq * 4 + 1] = fmaf(w, gv.y, acc[qq * 4 + 1]);
        acc[qq * 4 + 2] = fmaf(w, gv.z, acc[qq * 4 + 2]);
        acc[qq * 4 + 3] = fmaf(w, gv.w, acc[qq * 4 + 3]);
      }
    }
    float4* hp = reinterpret_cast<float4*>(&h0[o * 36 + kb]);
#pragma unroll
    for (int qq = 0; qq < 4; ++qq) {
      float4 hv;
      hv.x = fmaxf(acc[qq * 4 + 0], 0.f);
      hv.y = fmaxf(acc[qq * 4 + 1], 0.f);
      hv.z = fmaxf(acc[qq * 4 + 2], 0.f);
      hv.w = fmaxf(acc[qq * 4 + 3], 0.f);
      hp[qq] = hv;
    }
  }
  __syncthreads();
  // layer1: pooled[o2] = max_k relu(sum_o W1[o2,o]*h0[o,k] + b1[o2])
  {
    const int o2 = t;
    float acc[32];
    float bb = b1[o2];
#pragma unroll
    for (int j = 0; j < 32; ++j) acc[j] = bb;
    for (int o = 0; o < 128; ++o) {
      float w = w1t[o * 256 + o2];
      const float4* hp = reinterpret_cast<const float4*>(&h0[o * 36]);
#pragma unroll
      for (int qq = 0; qq < 8; ++qq) {
        float4 hv = hp[qq];
        acc[qq * 4 + 0] = fmaf(w, hv.x, acc[qq * 4 + 0]);
        acc[qq * 4 + 1] = fmaf(w, hv.y, acc[qq * 4 + 1]);
        acc[qq * 4 + 2] = fmaf(w, hv.z, acc[qq * 4 + 2]);
        acc[qq * 4 + 3] = fmaf(w, hv.w, acc[qq * 4 + 3]);
      }
    }
    float mx = 0.f; // relu floor
#pragma unroll
    for (int k = 0; k < 32; ++k) mx = fmaxf(mx, acc[k]);
    out[OUT_POOLED + ((size_t)(b * 256 + o2)) * NM + m] = mx;
  }
}

extern "C" void kernel_launch(void* const* d_in, const int* in_sizes, int n_in,
                              void* d_out, int out_size, void* d_ws, size_t ws_size,
                              hipStream_t stream) {
  const float* xyz    = (const float*)d_in[0];
  const float* feat   = (const float*)d_in[1];
  const float* prompt = (const float*)d_in[2];
  const float* projw  = (const float*)d_in[3];
  const float* projb  = (const float*)d_in[4];
  const float* lng    = (const float*)d_in[5];
  const float* lnb    = (const float*)d_in[6];
  const float* pww    = (const float*)d_in[7];
  const float* pwb    = (const float*)d_in[8];
  const float* w0     = (const float*)d_in[9];
  const float* b0     = (const float*)d_in[10];
  const float* w1     = (const float*)d_in[11];
  const float* b1     = (const float*)d_in[12];
  float* ws = (float*)d_ws;
  float* out = (float*)d_out;

  float* w0t     = ws + OFF_W0T;
  float* w1t     = ws + OFF_W1T;
  float* nxyz    = ws + OFF_NEWXYZ;
  int*   idxball = (int*)(ws + OFF_IDXBALL);
  int*   cnt     = (int*)(ws + OFF_CNT);
  float* emb     = ws + OFF_EMB;
  float* pwv     = ws + OFF_PW;
  float* pev     = ws + OFF_PE;

  hipMemsetAsync(cnt, 0, NB * NPTS * sizeof(int), stream);
  hipMemsetAsync(emb, 0, NB * 96 * sizeof(float), stream);

  k_prepw<<<128, 256, 0, stream>>>(w0, w1, w0t, w1t);
  k_fps<<<NB, 1024, 0, stream>>>(xyz, nxyz, out);
  k_ball<<<NB * NM / 4, 256, 0, stream>>>(xyz, nxyz, idxball, cnt, emb);
  k_embfeat<<<dim3(NC, NB), 256, 0, stream>>>(feat, cnt, emb);
  k_pe<<<NM, 64, 0, stream>>>(prompt, projw, projb, lng, lnb, pev);
  k_pw<<<NB, 1024, 0, stream>>>(emb, pww, pwb, pwv);
  k_main<<<NB * NM, 256, 0, stream>>>(feat, xyz, nxyz, idxball, pev, pwv,
                                      w0t, b0, w1t, b1, out);
}

// Round 6
// 2163.121 us; speedup vs baseline: 1.3118x; 1.3118x over previous
//
#include <hip/hip_runtime.h>
#include <hip/hip_bf16.h>

#define NB   4
#define NPTS 16384
#define NC   64
#define NM   1024
#define NK   32
#define NCP  67
#define RAD2 0.25f

// workspace offsets in 4-byte units (total ~323k floats = 1.29 MB)
#define OFF_W0T     0u        // 67*128 = 8576
#define OFF_W1T     8576u     // 128*256 = 32768
#define OFF_NEWXYZ  41344u    // 12288
#define OFF_IDXBALL 53632u    // 4*1024*32 = 131072 (int)
#define OFF_CNT     184704u   // 65536 (int)
#define OFF_EMB     250240u   // 384
#define OFF_PW      250624u   // 4096
#define OFF_PE      254720u   // 68608 -> ends 323328

// output offsets (FLOAT32 elements; d_out is float*)
#define OUT_NEWXYZ 0u
#define OUT_POOLED 12288u
#define OUT_IDX    1060864u

// ---------------- transpose weights ----------------
__global__ __launch_bounds__(256) void k_prepw(const float* __restrict__ w0,
                                               const float* __restrict__ w1,
                                               float* __restrict__ w0t,
                                               float* __restrict__ w1t) {
  int t = blockIdx.x * 256 + threadIdx.x;
  if (t < 128 * NCP) { int o = t / NCP, c = t % NCP; w0t[c * 128 + o] = w0[t]; }
  if (t < 256 * 128) { int o2 = t / 128, o = t % 128; w1t[o * 256 + o2] = w1[t]; }
}

// ---------------- furthest point sampling ----------------
// one block per batch; 512 threads, 32 points each (interleaved p = t+512*i).
// All coords + running min-dist in REGISTERS (launch_bounds(512,1) raises the
// VGPR cap to 512 so the 128-element arrays stay resident) -> inner loop has
// ZERO DS-pipe ops. Argmax reduce uses a packed u64 key
// (f32bits(best)<<32 | (16383-bidx)): non-negative f32 bits are monotone, so
// u64 max == (max value, min index) lexicographic — bit-identical to
// numpy/jax argmax. Winner z via unique-owner-lane LDS write (no shuffle);
// winner (x,y) via one broadcast ds_read from an LDS copy. One barrier/step,
// ping-ponged candidate buffers.
__global__ __launch_bounds__(512, 1) void k_fps(const float* __restrict__ xyz,
                                                float* __restrict__ newxyz,
                                                float* __restrict__ out) {
  const int b = blockIdx.x;
  const int t = threadIdx.x;
  const float* xb = xyz + (size_t)b * NPTS * 3;
  __shared__ float2 sxy[NPTS];                 // 128 KiB, winner lookup only
  __shared__ unsigned long long c_key[2][8];
  __shared__ float c_z[2][8];
  float px[32], py[32], pz[32], md[32];
#pragma unroll
  for (int i = 0; i < 32; ++i) {
    int p = t + 512 * i;
    px[i] = xb[p * 3 + 0];
    py[i] = xb[p * 3 + 1];
    pz[i] = xb[p * 3 + 2];
    sxy[p] = make_float2(px[i], py[i]);
    md[i] = 1e10f;
  }
  float lx = xb[0], ly = xb[1], lz = xb[2];
  if (t == 0) {
    newxyz[(size_t)b * NM * 3 + 0] = lx;
    newxyz[(size_t)b * NM * 3 + 1] = ly;
    newxyz[(size_t)b * NM * 3 + 2] = lz;
    out[OUT_NEWXYZ + (size_t)b * NM * 3 + 0] = lx;
    out[OUT_NEWXYZ + (size_t)b * NM * 3 + 1] = ly;
    out[OUT_NEWXYZ + (size_t)b * NM * 3 + 2] = lz;
    out[OUT_IDX + b * NM] = 0.0f;
  }
  __syncthreads();
  const int wid = t >> 6;
  for (int s = 1; s < NM; ++s) {
    float best = -1.0f;
    int   bidx = 0;
    float bz   = 0.0f;
#pragma unroll
    for (int i = 0; i < 32; ++i) {
      float dx = __fsub_rn(px[i], lx);
      float dy = __fsub_rn(py[i], ly);
      float dz = __fsub_rn(pz[i], lz);
      float d2 = __fadd_rn(__fadd_rn(__fmul_rn(dx, dx), __fmul_rn(dy, dy)),
                           __fmul_rn(dz, dz));
      float m0 = fminf(md[i], d2);
      md[i] = m0;
      bool gt = m0 > best;               // strict > : first (smallest p) max kept
      best = gt ? m0 : best;
      bidx = gt ? (t + 512 * i) : bidx;
      bz   = gt ? pz[i] : bz;
    }
    // packed key: value bits high, (16383 - idx) low  => u64 max = argmax w/ min-idx tiebreak
    unsigned long long key =
        ((unsigned long long)__float_as_uint(best) << 32) |
        (unsigned long long)(unsigned)(16383 - bidx);
    unsigned long long kr = key;
#pragma unroll
    for (int off = 1; off < 64; off <<= 1) {
      unsigned long long ok = __shfl_xor(kr, off);
      kr = ok > kr ? ok : kr;
    }
    const int pp = s & 1;
    if ((t & 63) == 0) c_key[pp][wid] = kr;
    if (key == kr) c_z[pp][wid] = bz;    // unique owner lane writes winner z
    __syncthreads();
    // fold the 8 wave candidates: 3-stage u64 shuffle butterfly
    unsigned long long k = c_key[pp][t & 7];
#pragma unroll
    for (int off = 1; off < 8; off <<= 1) {
      unsigned long long ok = __shfl_xor(k, off);
      k = ok > k ? ok : k;
    }
    const int bi = 16383 - (int)(unsigned)(k & 0xffffffffull);
    float2 cxy = sxy[bi];                 // broadcast LDS read
    lx = cxy.x;
    ly = cxy.y;
    lz = c_z[pp][(bi >> 6) & 7];          // owner wave's z
    if (t == 0) {
      newxyz[((size_t)b * NM + s) * 3 + 0] = lx;
      newxyz[((size_t)b * NM + s) * 3 + 1] = ly;
      newxyz[((size_t)b * NM + s) * 3 + 2] = lz;
      out[OUT_NEWXYZ + ((size_t)b * NM + s) * 3 + 0] = lx;
      out[OUT_NEWXYZ + ((size_t)b * NM + s) * 3 + 1] = ly;
      out[OUT_NEWXYZ + ((size_t)b * NM + s) * 3 + 2] = lz;
      out[OUT_IDX + b * NM + s] = (float)bi;
    }
  }
}

// ---------------- ball query: first NK indices with d2<=r2, pad with first ----
// one wave per (b,m); also histogram counts + xyz partial sums for emb.
__global__ __launch_bounds__(256) void k_ball(const float* __restrict__ xyz,
                                              const float* __restrict__ newxyz,
                                              int* __restrict__ idxball,
                                              int* __restrict__ cnt,
                                              float* __restrict__ emb) {
  __shared__ int s_idx[4][NK];
  const int lane = threadIdx.x & 63, wid = threadIdx.x >> 6;
  const int gid = blockIdx.x * 4 + wid; // (b,m)
  const int b = gid >> 10;
  const float* xb = xyz + (size_t)b * NPTS * 3;
  const float cx = newxyz[gid * 3 + 0];
  const float cy = newxyz[gid * 3 + 1];
  const float cz = newxyz[gid * 3 + 2];
  int total = 0;
  for (int base = 0; base < NPTS && total < NK; base += 64) {
    int n = base + lane;
    float dx = __fsub_rn(xb[n * 3 + 0], cx);
    float dy = __fsub_rn(xb[n * 3 + 1], cy);
    float dz = __fsub_rn(xb[n * 3 + 2], cz);
    float d2 = __fadd_rn(__fadd_rn(__fmul_rn(dx, dx), __fmul_rn(dy, dy)),
                         __fmul_rn(dz, dz));
    bool hit = d2 <= RAD2;
    unsigned long long mask = __ballot(hit);
    int pos = total + (int)__popcll(mask & ((1ull << lane) - 1ull));
    if (hit && pos < NK) s_idx[wid][pos] = n;
    total += (int)__popcll(mask);
  }
  int tt = total < NK ? total : NK;
  if (lane >= tt && lane < NK) s_idx[wid][lane] = s_idx[wid][0];
  int v = 0;
  if (lane < NK) {
    v = s_idx[wid][lane];
    idxball[(size_t)gid * NK + lane] = v;
    atomicAdd(&cnt[b * NPTS + v], 1);
  }
  float sx = 0.f, sy = 0.f, sz = 0.f;
  if (lane < NK) { sx = xb[v * 3 + 0]; sy = xb[v * 3 + 1]; sz = xb[v * 3 + 2]; }
#pragma unroll
  for (int off = 1; off < 64; off <<= 1) {
    sx += __shfl_xor(sx, off);
    sy += __shfl_xor(sy, off);
    sz += __shfl_xor(sz, off);
  }
  if (lane == 0) {
    atomicAdd(&emb[b * 96 + 0], sx - 32.0f * cx);
    atomicAdd(&emb[b * 96 + 1], sy - 32.0f * cy);
    atomicAdd(&emb[b * 96 + 2], sz - 32.0f * cz);
  }
}

// ---------------- emb feature part: emb[b,3+c] = sum_n cnt[b,n]*feat[b,c,n] ----
__global__ __launch_bounds__(256) void k_embfeat(const float* __restrict__ feat,
                                                 const int* __restrict__ cnt,
                                                 float* __restrict__ emb) {
  const int c = blockIdx.x, b = blockIdx.y;
  const float* f = feat + ((size_t)b * NC + c) * NPTS;
  const int* ct = cnt + b * NPTS;
  float acc = 0.f;
  for (int n = threadIdx.x; n < NPTS; n += 256)
    acc = fmaf((float)ct[n], f[n], acc);
  __shared__ float red[4];
#pragma unroll
  for (int off = 1; off < 64; off <<= 1) acc += __shfl_xor(acc, off);
  if ((threadIdx.x & 63) == 0) red[threadIdx.x >> 6] = acc;
  __syncthreads();
  if (threadIdx.x == 0)
    emb[b * 96 + 3 + c] = red[0] + red[1] + red[2] + red[3];
}

// ---------------- pe: proj + layernorm + exact gelu ----------------
__global__ __launch_bounds__(64) void k_pe(const float* __restrict__ prompt,
                                           const float* __restrict__ projw,
                                           const float* __restrict__ projb,
                                           const float* __restrict__ lng,
                                           const float* __restrict__ lnb,
                                           float* __restrict__ pe) {
  const int m = blockIdx.x, lane = threadIdx.x;
  const float p0 = prompt[m * 2 + 0], p1 = prompt[m * 2 + 1];
  const int c1 = lane, c2 = lane + 64;
  float v1 = p0 * projw[c1 * 2 + 0] + p1 * projw[c1 * 2 + 1] + projb[c1];
  float v2 = 0.f;
  if (c2 < NCP) v2 = p0 * projw[c2 * 2 + 0] + p1 * projw[c2 * 2 + 1] + projb[c2];
  float s = v1 + ((c2 < NCP) ? v2 : 0.f);
#pragma unroll
  for (int off = 1; off < 64; off <<= 1) s += __shfl_xor(s, off);
  float mu = s * (1.0f / 67.0f);
  float d1 = v1 - mu;
  float d2v = (c2 < NCP) ? (v2 - mu) : 0.f;
  float q = d1 * d1 + d2v * d2v;
#pragma unroll
  for (int off = 1; off < 64; off <<= 1) q += __shfl_xor(q, off);
  float inv = 1.0f / sqrtf(q * (1.0f / 67.0f) + 1e-5f);
  {
    float y = d1 * inv * lng[c1] + lnb[c1];
    pe[m * NCP + c1] = 0.5f * y * (1.0f + erff(y * 0.70710678118654752f));
  }
  if (c2 < NCP) {
    float y = (v2 - mu) * inv * lng[c2] + lnb[c2];
    pe[m * NCP + c2] = 0.5f * y * (1.0f + erff(y * 0.70710678118654752f));
  }
}

// ---------------- pw: softmax(emb/32768 @ pw_w.T + pw_b) ----------------
__global__ __launch_bounds__(1024) void k_pw(const float* __restrict__ emb,
                                             const float* __restrict__ pww,
                                             const float* __restrict__ pwb,
                                             float* __restrict__ pw) {
  const int b = blockIdx.x, m = threadIdx.x;
  __shared__ float se[NCP];
  __shared__ float red[16];
  __shared__ float bcast;
  if (m < NCP) se[m] = emb[b * 96 + m] * (1.0f / 32768.0f);
  __syncthreads();
  float acc = pwb[m];
  for (int c = 0; c < NCP; ++c) acc = fmaf(se[c], pww[m * NCP + c], acc);
  float mx = acc;
#pragma unroll
  for (int off = 1; off < 64; off <<= 1) mx = fmaxf(mx, __shfl_xor(mx, off));
  if ((m & 63) == 0) red[m >> 6] = mx;
  __syncthreads();
  if (m == 0) {
    float v = red[0];
    for (int w = 1; w < 16; ++w) v = fmaxf(v, red[w]);
    bcast = v;
  }
  __syncthreads();
  float e = expf(acc - bcast);
  float ssum = e;
#pragma unroll
  for (int off = 1; off < 64; off <<= 1) ssum += __shfl_xor(ssum, off);
  if ((m & 63) == 0) red[m >> 6] = ssum;
  __syncthreads();
  if (m == 0) {
    float v = 0.f;
    for (int w = 0; w < 16; ++w) v += red[w];
    bcast = v;
  }
  __syncthreads();
  pw[b * NM + m] = e / bcast;
}

// ---------------- fused gather + pe*pw + conv0 + conv1 + maxpool ----------------
__global__ __launch_bounds__(256) void k_main(const float* __restrict__ feat,
                                              const float* __restrict__ xyz,
                                              const float* __restrict__ newxyz,
                                              const int* __restrict__ idxball,
                                              const float* __restrict__ pe,
                                              const float* __restrict__ pwbuf,
                                              const float* __restrict__ w0t,
                                              const float* __restrict__ b0,
                                              const float* __restrict__ w1t,
                                              const float* __restrict__ b1,
                                              float* __restrict__ out) {
  __shared__ __align__(16) float g[NCP * 36];
  __shared__ __align__(16) float h0[128 * 36];
  __shared__ int s_idx[NK];
  __shared__ float spe[NCP];
  const int bid = blockIdx.x;
  const int b = bid >> 10, m = bid & 1023;
  const int t = threadIdx.x;
  const float pwv = pwbuf[bid];
  if (t < NK) {
    int n = idxball[(size_t)bid * NK + t];
    n = n < 0 ? 0 : (n > NPTS - 1 ? NPTS - 1 : n); // insurance clamp
    s_idx[t] = n;
  }
  if (t < NCP) spe[t] = pe[m * NCP + t] * pwv;
  __syncthreads();
  // stage feature rows of g (gather from native (B,C,N) layout; L3-resident)
  for (int e = t; e < NK * NC; e += 256) {
    int k = e >> 6, c = e & 63;
    int n = s_idx[k];
    g[(3 + c) * 36 + k] = feat[((size_t)b * NC + c) * NPTS + n] + spe[3 + c];
  }
  // stage xyz rows of g
  if (t < 96) {
    int k = t & 31, d = t >> 5;
    int n = s_idx[k];
    float cv = newxyz[bid * 3 + d];
    g[d * 36 + k] = (xyz[((size_t)b * NPTS + n) * 3 + d] - cv) + spe[d];
  }
  __syncthreads();
  // layer0: h0[o][k] = relu(sum_c W0[o,c]*g[c,k] + b0[o])
  {
    const int o = t & 127, kb = (t >> 7) * 16;
    float acc[16];
    float bb = b0[o];
#pragma unroll
    for (int j = 0; j < 16; ++j) acc[j] = bb;
    for (int c = 0; c < NCP; ++c) {
      float w = w0t[c * 128 + o];
      const float4* gp = reinterpret_cast<const float4*>(&g[c * 36 + kb]);
#pragma unroll
      for (int qq = 0; qq < 4; ++qq) {
        float4 gv = gp[qq];
        acc[qq * 4 + 0] = fmaf(w, gv.x, acc[qq * 4 + 0]);
        acc[qq * 4 + 1] = fmaf(w, gv.y, acc[qq * 4 + 1]);
        acc[qq * 4 + 2] = fmaf(w, gv.z, acc[qq * 4 + 2]);
        acc[qq * 4 + 3] = fmaf(w, gv.w, acc[qq * 4 + 3]);
      }
    }
    float4* hp = reinterpret_cast<float4*>(&h0[o * 36 + kb]);
#pragma unroll
    for (int qq = 0; qq < 4; ++qq) {
      float4 hv;
      hv.x = fmaxf(acc[qq * 4 + 0], 0.f);
      hv.y = fmaxf(acc[qq * 4 + 1], 0.f);
      hv.z = fmaxf(acc[qq * 4 + 2], 0.f);
      hv.w = fmaxf(acc[qq * 4 + 3], 0.f);
      hp[qq] = hv;
    }
  }
  __syncthreads();
  // layer1: pooled[o2] = max_k relu(sum_o W1[o2,o]*h0[o,k] + b1[o2])
  {
    const int o2 = t;
    float acc[32];
    float bb = b1[o2];
#pragma unroll
    for (int j = 0; j < 32; ++j) acc[j] = bb;
    for (int o = 0; o < 128; ++o) {
      float w = w1t[o * 256 + o2];
      const float4* hp = reinterpret_cast<const float4*>(&h0[o * 36]);
#pragma unroll
      for (int qq = 0; qq < 8; ++qq) {
        float4 hv = hp[qq];
        acc[qq * 4 + 0] = fmaf(w, hv.x, acc[qq * 4 + 0]);
        acc[qq * 4 + 1] = fmaf(w, hv.y, acc[qq * 4 + 1]);
        acc[qq * 4 + 2] = fmaf(w, hv.z, acc[qq * 4 + 2]);
        acc[qq * 4 + 3] = fmaf(w, hv.w, acc[qq * 4 + 3]);
      }
    }
    float mx = 0.f; // relu floor
#pragma unroll
    for (int k = 0; k < 32; ++k) mx = fmaxf(mx, acc[k]);
    out[OUT_POOLED + ((size_t)(b * 256 + o2)) * NM + m] = mx;
  }
}

extern "C" void kernel_launch(void* const* d_in, const int* in_sizes, int n_in,
                              void* d_out, int out_size, void* d_ws, size_t ws_size,
                              hipStream_t stream) {
  const float* xyz    = (const float*)d_in[0];
  const float* feat   = (const float*)d_in[1];
  const float* prompt = (const float*)d_in[2];
  const float* projw  = (const float*)d_in[3];
  const float* projb  = (const float*)d_in[4];
  const float* lng    = (const float*)d_in[5];
  const float* lnb    = (const float*)d_in[6];
  const float* pww    = (const float*)d_in[7];
  const float* pwb    = (const float*)d_in[8];
  const float* w0     = (const float*)d_in[9];
  const float* b0     = (const float*)d_in[10];
  const float* w1     = (const float*)d_in[11];
  const float* b1     = (const float*)d_in[12];
  float* ws = (float*)d_ws;
  float* out = (float*)d_out;

  float* w0t     = ws + OFF_W0T;
  float* w1t     = ws + OFF_W1T;
  float* nxyz    = ws + OFF_NEWXYZ;
  int*   idxball = (int*)(ws + OFF_IDXBALL);
  int*   cnt     = (int*)(ws + OFF_CNT);
  float* emb     = ws + OFF_EMB;
  float* pwv     = ws + OFF_PW;
  float* pev     = ws + OFF_PE;

  hipMemsetAsync(cnt, 0, NB * NPTS * sizeof(int), stream);
  hipMemsetAsync(emb, 0, NB * 96 * sizeof(float), stream);

  k_prepw<<<128, 256, 0, stream>>>(w0, w1, w0t, w1t);
  k_fps<<<NB, 512, 0, stream>>>(xyz, nxyz, out);
  k_ball<<<NB * NM / 4, 256, 0, stream>>>(xyz, nxyz, idxball, cnt, emb);
  k_embfeat<<<dim3(NC, NB), 256, 0, stream>>>(feat, cnt, emb);
  k_pe<<<NM, 64, 0, stream>>>(prompt, projw, projb, lng, lnb, pev);
  k_pw<<<NB, 1024, 0, stream>>>(emb, pww, pwb, pwv);
  k_main<<<NB * NM, 256, 0, stream>>>(feat, xyz, nxyz, idxball, pev, pwv,
                                      w0t, b0, w1t, b1, out);
}

// Round 7
// 1994.564 us; speedup vs baseline: 1.4227x; 1.0845x over previous
//
#include <hip/hip_runtime.h>
#include <hip/hip_bf16.h>

#define NB   4
#define NPTS 16384
#define NC   64
#define NM   1024
#define NK   32
#define NCP  67
#define RAD2 0.25f

// workspace offsets in 4-byte units (total ~323k floats = 1.29 MB)
#define OFF_W0T     0u        // 67*128 = 8576
#define OFF_W1T     8576u     // 128*256 = 32768
#define OFF_NEWXYZ  41344u    // 12288
#define OFF_IDXBALL 53632u    // 4*1024*32 = 131072 (int)
#define OFF_CNT     184704u   // 65536 (int)
#define OFF_EMB     250240u   // 384
#define OFF_PW      250624u   // 4096
#define OFF_PE      254720u   // 68608 -> ends 323328

// output offsets (FLOAT32 elements; d_out is float*)
#define OUT_NEWXYZ 0u
#define OUT_POOLED 12288u
#define OUT_IDX    1060864u

// ---------------- transpose weights ----------------
__global__ __launch_bounds__(256) void k_prepw(const float* __restrict__ w0,
                                               const float* __restrict__ w1,
                                               float* __restrict__ w0t,
                                               float* __restrict__ w1t) {
  int t = blockIdx.x * 256 + threadIdx.x;
  if (t < 128 * NCP) { int o = t / NCP, c = t % NCP; w0t[c * 128 + o] = w0[t]; }
  if (t < 256 * 128) { int o2 = t / 128, o = t % 128; w1t[o * 256 + o2] = w1[t]; }
}

// ---------------- furthest point sampling ----------------
// one block per batch; 512 threads, 32 points each (interleaved p = t+512*i).
// All coords + running min-dist live in 128 NAMED scalar registers (macro-
// generated, no arrays -> nothing for the compiler to demote to scratch; no
// LDS copy -> nothing to rematerialize from). Inner loop: 13 VALU ops, zero
// DS/VMEM. Argmax via packed u64 key (f32bits<<32 | (16383-idx)): u64 max ==
// (max value, min index) — bit-identical to numpy/jax argmax incl. ties.
// Wave butterfly (u64 shfl) -> leader writes key -> one barrier -> all lanes
// fold 8 keys via broadcast LDS reads + in-register max; winner coords come
// from a broadcast global L2 load. Ping-ponged key buffer keeps WAR safe.
// Distances use explicit non-FMA f32 ops, (dx*dx+dy*dy)+dz*dz order.
__device__ __forceinline__ unsigned long long umax64(unsigned long long a,
                                                     unsigned long long b) {
  return a > b ? a : b;
}

#define FPS_DECL(i) float px##i, py##i, pz##i, md##i;
#define FPS_INIT(i) { int p = t + 512 * (i); \
  px##i = xb[p * 3 + 0]; py##i = xb[p * 3 + 1]; pz##i = xb[p * 3 + 2]; \
  md##i = 1e10f; }
#define FPS_UPD(i) { \
  float dx = __fsub_rn(px##i, lx); \
  float dy = __fsub_rn(py##i, ly); \
  float dz = __fsub_rn(pz##i, lz); \
  float d2 = __fadd_rn(__fadd_rn(__fmul_rn(dx, dx), __fmul_rn(dy, dy)), \
                       __fmul_rn(dz, dz)); \
  float m0 = fminf(md##i, d2); \
  md##i = m0; \
  bool gt = m0 > best; \
  best = gt ? m0 : best; \
  klo  = gt ? (kbase - 512u * (i)) : klo; }
#define FPS_REP32(M) M(0) M(1) M(2) M(3) M(4) M(5) M(6) M(7) \
  M(8) M(9) M(10) M(11) M(12) M(13) M(14) M(15) \
  M(16) M(17) M(18) M(19) M(20) M(21) M(22) M(23) \
  M(24) M(25) M(26) M(27) M(28) M(29) M(30) M(31)

__global__ __launch_bounds__(512, 1) void k_fps(const float* __restrict__ xyz,
                                                float* __restrict__ newxyz,
                                                float* __restrict__ out) {
  const int b = blockIdx.x;
  const int t = threadIdx.x;
  const float* xb = xyz + (size_t)b * NPTS * 3;
  __shared__ __align__(16) unsigned long long c_key[2][8];
  FPS_REP32(FPS_DECL)
  FPS_REP32(FPS_INIT)
  float lx = xb[0], ly = xb[1], lz = xb[2];
  if (t == 0) {
    newxyz[(size_t)b * NM * 3 + 0] = lx;
    newxyz[(size_t)b * NM * 3 + 1] = ly;
    newxyz[(size_t)b * NM * 3 + 2] = lz;
    out[OUT_NEWXYZ + (size_t)b * NM * 3 + 0] = lx;
    out[OUT_NEWXYZ + (size_t)b * NM * 3 + 1] = ly;
    out[OUT_NEWXYZ + (size_t)b * NM * 3 + 2] = lz;
    out[OUT_IDX + b * NM] = 0.0f;
  }
  __syncthreads();
  const int wid = t >> 6;
  const unsigned kbase = 16383u - (unsigned)t;   // klo = 16383 - idx
  for (int s = 1; s < NM; ++s) {
    float best = -1.0f;
    unsigned klo = 0u;
    FPS_REP32(FPS_UPD)
    unsigned long long kr =
        ((unsigned long long)__float_as_uint(best) << 32) |
        (unsigned long long)klo;
#pragma unroll
    for (int off = 1; off < 64; off <<= 1) {
      unsigned long long ok = __shfl_xor(kr, off);
      kr = ok > kr ? ok : kr;
    }
    const int pp = s & 1;
    if ((t & 63) == 0) c_key[pp][wid] = kr;
    __syncthreads();
    // fold 8 wave candidates: broadcast LDS reads + in-register u64 max
    const ulonglong2* ck = reinterpret_cast<const ulonglong2*>(&c_key[pp][0]);
    ulonglong2 k01 = ck[0], k23 = ck[1], k45 = ck[2], k67 = ck[3];
    unsigned long long k =
        umax64(umax64(umax64(k01.x, k01.y), umax64(k23.x, k23.y)),
               umax64(umax64(k45.x, k45.y), umax64(k67.x, k67.y)));
    const int bi = 16383 - (int)(unsigned)(k & 0xffffffffull);
    // broadcast L2 load of the winner's coords (same addr across lanes)
    lx = xb[bi * 3 + 0];
    ly = xb[bi * 3 + 1];
    lz = xb[bi * 3 + 2];
    if (t == 0) {
      newxyz[((size_t)b * NM + s) * 3 + 0] = lx;
      newxyz[((size_t)b * NM + s) * 3 + 1] = ly;
      newxyz[((size_t)b * NM + s) * 3 + 2] = lz;
      out[OUT_NEWXYZ + ((size_t)b * NM + s) * 3 + 0] = lx;
      out[OUT_NEWXYZ + ((size_t)b * NM + s) * 3 + 1] = ly;
      out[OUT_NEWXYZ + ((size_t)b * NM + s) * 3 + 2] = lz;
      out[OUT_IDX + b * NM + s] = (float)bi;
    }
  }
}

// ---------------- ball query: first NK indices with d2<=r2, pad with first ----
// one wave per (b,m); also histogram counts + xyz partial sums for emb.
__global__ __launch_bounds__(256) void k_ball(const float* __restrict__ xyz,
                                              const float* __restrict__ newxyz,
                                              int* __restrict__ idxball,
                                              int* __restrict__ cnt,
                                              float* __restrict__ emb) {
  __shared__ int s_idx[4][NK];
  const int lane = threadIdx.x & 63, wid = threadIdx.x >> 6;
  const int gid = blockIdx.x * 4 + wid; // (b,m)
  const int b = gid >> 10;
  const float* xb = xyz + (size_t)b * NPTS * 3;
  const float cx = newxyz[gid * 3 + 0];
  const float cy = newxyz[gid * 3 + 1];
  const float cz = newxyz[gid * 3 + 2];
  int total = 0;
  for (int base = 0; base < NPTS && total < NK; base += 64) {
    int n = base + lane;
    float dx = __fsub_rn(xb[n * 3 + 0], cx);
    float dy = __fsub_rn(xb[n * 3 + 1], cy);
    float dz = __fsub_rn(xb[n * 3 + 2], cz);
    float d2 = __fadd_rn(__fadd_rn(__fmul_rn(dx, dx), __fmul_rn(dy, dy)),
                         __fmul_rn(dz, dz));
    bool hit = d2 <= RAD2;
    unsigned long long mask = __ballot(hit);
    int pos = total + (int)__popcll(mask & ((1ull << lane) - 1ull));
    if (hit && pos < NK) s_idx[wid][pos] = n;
    total += (int)__popcll(mask);
  }
  int tt = total < NK ? total : NK;
  if (lane >= tt && lane < NK) s_idx[wid][lane] = s_idx[wid][0];
  int v = 0;
  if (lane < NK) {
    v = s_idx[wid][lane];
    idxball[(size_t)gid * NK + lane] = v;
    atomicAdd(&cnt[b * NPTS + v], 1);
  }
  float sx = 0.f, sy = 0.f, sz = 0.f;
  if (lane < NK) { sx = xb[v * 3 + 0]; sy = xb[v * 3 + 1]; sz = xb[v * 3 + 2]; }
#pragma unroll
  for (int off = 1; off < 64; off <<= 1) {
    sx += __shfl_xor(sx, off);
    sy += __shfl_xor(sy, off);
    sz += __shfl_xor(sz, off);
  }
  if (lane == 0) {
    atomicAdd(&emb[b * 96 + 0], sx - 32.0f * cx);
    atomicAdd(&emb[b * 96 + 1], sy - 32.0f * cy);
    atomicAdd(&emb[b * 96 + 2], sz - 32.0f * cz);
  }
}

// ---------------- emb feature part: emb[b,3+c] = sum_n cnt[b,n]*feat[b,c,n] ----
__global__ __launch_bounds__(256) void k_embfeat(const float* __restrict__ feat,
                                                 const int* __restrict__ cnt,
                                                 float* __restrict__ emb) {
  const int c = blockIdx.x, b = blockIdx.y;
  const float* f = feat + ((size_t)b * NC + c) * NPTS;
  const int* ct = cnt + b * NPTS;
  float acc = 0.f;
  for (int n = threadIdx.x; n < NPTS; n += 256)
    acc = fmaf((float)ct[n], f[n], acc);
  __shared__ float red[4];
#pragma unroll
  for (int off = 1; off < 64; off <<= 1) acc += __shfl_xor(acc, off);
  if ((threadIdx.x & 63) == 0) red[threadIdx.x >> 6] = acc;
  __syncthreads();
  if (threadIdx.x == 0)
    emb[b * 96 + 3 + c] = red[0] + red[1] + red[2] + red[3];
}

// ---------------- pe: proj + layernorm + exact gelu ----------------
__global__ __launch_bounds__(64) void k_pe(const float* __restrict__ prompt,
                                           const float* __restrict__ projw,
                                           const float* __restrict__ projb,
                                           const float* __restrict__ lng,
                                           const float* __restrict__ lnb,
                                           float* __restrict__ pe) {
  const int m = blockIdx.x, lane = threadIdx.x;
  const float p0 = prompt[m * 2 + 0], p1 = prompt[m * 2 + 1];
  const int c1 = lane, c2 = lane + 64;
  float v1 = p0 * projw[c1 * 2 + 0] + p1 * projw[c1 * 2 + 1] + projb[c1];
  float v2 = 0.f;
  if (c2 < NCP) v2 = p0 * projw[c2 * 2 + 0] + p1 * projw[c2 * 2 + 1] + projb[c2];
  float s = v1 + ((c2 < NCP) ? v2 : 0.f);
#pragma unroll
  for (int off = 1; off < 64; off <<= 1) s += __shfl_xor(s, off);
  float mu = s * (1.0f / 67.0f);
  float d1 = v1 - mu;
  float d2v = (c2 < NCP) ? (v2 - mu) : 0.f;
  float q = d1 * d1 + d2v * d2v;
#pragma unroll
  for (int off = 1; off < 64; off <<= 1) q += __shfl_xor(q, off);
  float inv = 1.0f / sqrtf(q * (1.0f / 67.0f) + 1e-5f);
  {
    float y = d1 * inv * lng[c1] + lnb[c1];
    pe[m * NCP + c1] = 0.5f * y * (1.0f + erff(y * 0.70710678118654752f));
  }
  if (c2 < NCP) {
    float y = (v2 - mu) * inv * lng[c2] + lnb[c2];
    pe[m * NCP + c2] = 0.5f * y * (1.0f + erff(y * 0.70710678118654752f));
  }
}

// ---------------- pw: softmax(emb/32768 @ pw_w.T + pw_b) ----------------
__global__ __launch_bounds__(1024) void k_pw(const float* __restrict__ emb,
                                             const float* __restrict__ pww,
                                             const float* __restrict__ pwb,
                                             float* __restrict__ pw) {
  const int b = blockIdx.x, m = threadIdx.x;
  __shared__ float se[NCP];
  __shared__ float red[16];
  __shared__ float bcast;
  if (m < NCP) se[m] = emb[b * 96 + m] * (1.0f / 32768.0f);
  __syncthreads();
  float acc = pwb[m];
  for (int c = 0; c < NCP; ++c) acc = fmaf(se[c], pww[m * NCP + c], acc);
  float mx = acc;
#pragma unroll
  for (int off = 1; off < 64; off <<= 1) mx = fmaxf(mx, __shfl_xor(mx, off));
  if ((m & 63) == 0) red[m >> 6] = mx;
  __syncthreads();
  if (m == 0) {
    float v = red[0];
    for (int w = 1; w < 16; ++w) v = fmaxf(v, red[w]);
    bcast = v;
  }
  __syncthreads();
  float e = expf(acc - bcast);
  float ssum = e;
#pragma unroll
  for (int off = 1; off < 64; off <<= 1) ssum += __shfl_xor(ssum, off);
  if ((m & 63) == 0) red[m >> 6] = ssum;
  __syncthreads();
  if (m == 0) {
    float v = 0.f;
    for (int w = 0; w < 16; ++w) v += red[w];
    bcast = v;
  }
  __syncthreads();
  pw[b * NM + m] = e / bcast;
}

// ---------------- fused gather + pe*pw + conv0 + conv1 + maxpool ----------------
__global__ __launch_bounds__(256) void k_main(const float* __restrict__ feat,
                                              const float* __restrict__ xyz,
                                              const float* __restrict__ newxyz,
                                              const int* __restrict__ idxball,
                                              const float* __restrict__ pe,
                                              const float* __restrict__ pwbuf,
                                              const float* __restrict__ w0t,
                                              const float* __restrict__ b0,
                                              const float* __restrict__ w1t,
                                              const float* __restrict__ b1,
                                              float* __restrict__ out) {
  __shared__ __align__(16) float g[NCP * 36];
  __shared__ __align__(16) float h0[128 * 36];
  __shared__ int s_idx[NK];
  __shared__ float spe[NCP];
  const int bid = blockIdx.x;
  const int b = bid >> 10, m = bid & 1023;
  const int t = threadIdx.x;
  const float pwv = pwbuf[bid];
  if (t < NK) {
    int n = idxball[(size_t)bid * NK + t];
    n = n < 0 ? 0 : (n > NPTS - 1 ? NPTS - 1 : n); // insurance clamp
    s_idx[t] = n;
  }
  if (t < NCP) spe[t] = pe[m * NCP + t] * pwv;
  __syncthreads();
  // stage feature rows of g (gather from native (B,C,N) layout; L3-resident)
  for (int e = t; e < NK * NC; e += 256) {
    int k = e >> 6, c = e & 63;
    int n = s_idx[k];
    g[(3 + c) * 36 + k] = feat[((size_t)b * NC + c) * NPTS + n] + spe[3 + c];
  }
  // stage xyz rows of g
  if (t < 96) {
    int k = t & 31, d = t >> 5;
    int n = s_idx[k];
    float cv = newxyz[bid * 3 + d];
    g[d * 36 + k] = (xyz[((size_t)b * NPTS + n) * 3 + d] - cv) + spe[d];
  }
  __syncthreads();
  // layer0: h0[o][k] = relu(sum_c W0[o,c]*g[c,k] + b0[o])
  {
    const int o = t & 127, kb = (t >> 7) * 16;
    float acc[16];
    float bb = b0[o];
#pragma unroll
    for (int j = 0; j < 16; ++j) acc[j] = bb;
    for (int c = 0; c < NCP; ++c) {
      float w = w0t[c * 128 + o];
      const float4* gp = reinterpret_cast<const float4*>(&g[c * 36 + kb]);
#pragma unroll
      for (int qq = 0; qq < 4; ++qq) {
        float4 gv = gp[qq];
        acc[qq * 4 + 0] = fmaf(w, gv.x, acc[qq * 4 + 0]);
        acc[qq * 4 + 1] = fmaf(w, gv.y, acc[qq * 4 + 1]);
        acc[qq * 4 + 2] = fmaf(w, gv.z, acc[qq * 4 + 2]);
        acc[qq * 4 + 3] = fmaf(w, gv.w, acc[qq * 4 + 3]);
      }
    }
    float4* hp = reinterpret_cast<float4*>(&h0[o * 36 + kb]);
#pragma unroll
    for (int qq = 0; qq < 4; ++qq) {
      float4 hv;
      hv.x = fmaxf(acc[qq * 4 + 0], 0.f);
      hv.y = fmaxf(acc[qq * 4 + 1], 0.f);
      hv.z = fmaxf(acc[qq * 4 + 2], 0.f);
      hv.w = fmaxf(acc[qq * 4 + 3], 0.f);
      hp[qq] = hv;
    }
  }
  __syncthreads();
  // layer1: pooled[o2] = max_k relu(sum_o W1[o2,o]*h0[o,k] + b1[o2])
  {
    const int o2 = t;
    float acc[32];
    float bb = b1[o2];
#pragma unroll
    for (int j = 0; j < 32; ++j) acc[j] = bb;
    for (int o = 0; o < 128; ++o) {
      float w = w1t[o * 256 + o2];
      const float4* hp = reinterpret_cast<const float4*>(&h0[o * 36]);
#pragma unroll
      for (int qq = 0; qq < 8; ++qq) {
        float4 hv = hp[qq];
        acc[qq * 4 + 0] = fmaf(w, hv.x, acc[qq * 4 + 0]);
        acc[qq * 4 + 1] = fmaf(w, hv.y, acc[qq * 4 + 1]);
        acc[qq * 4 + 2] = fmaf(w, hv.z, acc[qq * 4 + 2]);
        acc[qq * 4 + 3] = fmaf(w, hv.w, acc[qq * 4 + 3]);
      }
    }
    float mx = 0.f; // relu floor
#pragma unroll
    for (int k = 0; k < 32; ++k) mx = fmaxf(mx, acc[k]);
    out[OUT_POOLED + ((size_t)(b * 256 + o2)) * NM + m] = mx;
  }
}

extern "C" void kernel_launch(void* const* d_in, const int* in_sizes, int n_in,
                              void* d_out, int out_size, void* d_ws, size_t ws_size,
                              hipStream_t stream) {
  const float* xyz    = (const float*)d_in[0];
  const float* feat   = (const float*)d_in[1];
  const float* prompt = (const float*)d_in[2];
  const float* projw  = (const float*)d_in[3];
  const float* projb  = (const float*)d_in[4];
  const float* lng    = (const float*)d_in[5];
  const float* lnb    = (const float*)d_in[6];
  const float* pww    = (const float*)d_in[7];
  const float* pwb    = (const float*)d_in[8];
  const float* w0     = (const float*)d_in[9];
  const float* b0     = (const float*)d_in[10];
  const float* w1     = (const float*)d_in[11];
  const float* b1     = (const float*)d_in[12];
  float* ws = (float*)d_ws;
  float* out = (float*)d_out;

  float* w0t     = ws + OFF_W0T;
  float* w1t     = ws + OFF_W1T;
  float* nxyz    = ws + OFF_NEWXYZ;
  int*   idxball = (int*)(ws + OFF_IDXBALL);
  int*   cnt     = (int*)(ws + OFF_CNT);
  float* emb     = ws + OFF_EMB;
  float* pwv     = ws + OFF_PW;
  float* pev     = ws + OFF_PE;

  hipMemsetAsync(cnt, 0, NB * NPTS * sizeof(int), stream);
  hipMemsetAsync(emb, 0, NB * 96 * sizeof(float), stream);

  k_prepw<<<128, 256, 0, stream>>>(w0, w1, w0t, w1t);
  k_fps<<<NB, 512, 0, stream>>>(xyz, nxyz, out);
  k_ball<<<NB * NM / 4, 256, 0, stream>>>(xyz, nxyz, idxball, cnt, emb);
  k_embfeat<<<dim3(NC, NB), 256, 0, stream>>>(feat, cnt, emb);
  k_pe<<<NM, 64, 0, stream>>>(prompt, projw, projb, lng, lnb, pev);
  k_pw<<<NB, 1024, 0, stream>>>(emb, pww, pwb, pwv);
  k_main<<<NB * NM, 256, 0, stream>>>(feat, xyz, nxyz, idxball, pev, pwv,
                                      w0t, b0, w1t, b1, out);
}

// Round 8
// 1987.312 us; speedup vs baseline: 1.4279x; 1.0036x over previous
//
#include <hip/hip_runtime.h>
#include <hip/hip_bf16.h>

#define NB   4
#define NPTS 16384
#define NC   64
#define NM   1024
#define NK   32
#define NCP  67
#define RAD2 0.25f

// workspace offsets in 4-byte units (total ~323k floats = 1.29 MB)
#define OFF_W0T     0u        // 67*128 = 8576
#define OFF_W1T     8576u     // 128*256 = 32768
#define OFF_NEWXYZ  41344u    // 12288
#define OFF_IDXBALL 53632u    // 4*1024*32 = 131072 (int)
#define OFF_CNT     184704u   // 65536 (int)
#define OFF_EMB     250240u   // 384
#define OFF_PW      250624u   // 4096
#define OFF_PE      254720u   // 68608 -> ends 323328

// output offsets (FLOAT32 elements; d_out is float*)
#define OUT_NEWXYZ 0u
#define OUT_POOLED 12288u
#define OUT_IDX    1060864u

// ---------------- transpose weights ----------------
__global__ __launch_bounds__(256) void k_prepw(const float* __restrict__ w0,
                                               const float* __restrict__ w1,
                                               float* __restrict__ w0t,
                                               float* __restrict__ w1t) {
  int t = blockIdx.x * 256 + threadIdx.x;
  if (t < 128 * NCP) { int o = t / NCP, c = t % NCP; w0t[c * 128 + o] = w0[t]; }
  if (t < 256 * 128) { int o2 = t / 128, o = t % 128; w1t[o * 256 + o2] = w1[t]; }
}

// ---------------- furthest point sampling ----------------
// one block per batch; 512 threads, 32 points each (interleaved p = t+512*i).
// All coords + running min-dist live in 128 NAMED scalar registers. The c_key
// array is deliberately declared 128 KiB: at compile time the register
// allocator then knows only ONE block/CU can fit (2x128KiB > 160KiB LDS), so
// it stops trimming VGPRs for a hypothetical 2-block occupancy (r5-r7 all
// allocated at 2-block-friendly budgets 60/108/96 and spilled the state to
// scratch). Only the first 16 entries of c_key are used.
// Argmax via packed u64 key (f32bits<<32 | (16383-idx)): u64 max ==
// (max value, min index) — bit-identical to numpy/jax argmax incl. ties.
// Wave butterfly (u64 shfl) -> leader writes key -> one barrier -> all lanes
// fold 8 keys via broadcast LDS reads + in-register max; winner coords come
// from a broadcast global L2 load. Ping-ponged key buffer keeps WAR safe.
// Distances use explicit non-FMA f32 ops, (dx*dx+dy*dy)+dz*dz order.
__device__ __forceinline__ unsigned long long umax64(unsigned long long a,
                                                     unsigned long long b) {
  return a > b ? a : b;
}

#define FPS_DECL(i) float px##i, py##i, pz##i, md##i;
#define FPS_INIT(i) { int p = t + 512 * (i); \
  px##i = xb[p * 3 + 0]; py##i = xb[p * 3 + 1]; pz##i = xb[p * 3 + 2]; \
  md##i = 1e10f; }
#define FPS_UPD(i) { \
  float dx = __fsub_rn(px##i, lx); \
  float dy = __fsub_rn(py##i, ly); \
  float dz = __fsub_rn(pz##i, lz); \
  float d2 = __fadd_rn(__fadd_rn(__fmul_rn(dx, dx), __fmul_rn(dy, dy)), \
                       __fmul_rn(dz, dz)); \
  float m0 = fminf(md##i, d2); \
  md##i = m0; \
  bool gt = m0 > best; \
  best = gt ? m0 : best; \
  klo  = gt ? (kbase - 512u * (i)) : klo; }
#define FPS_REP32(M) M(0) M(1) M(2) M(3) M(4) M(5) M(6) M(7) \
  M(8) M(9) M(10) M(11) M(12) M(13) M(14) M(15) \
  M(16) M(17) M(18) M(19) M(20) M(21) M(22) M(23) \
  M(24) M(25) M(26) M(27) M(28) M(29) M(30) M(31)

__global__ __launch_bounds__(512, 1) void k_fps(const float* __restrict__ xyz,
                                                float* __restrict__ newxyz,
                                                float* __restrict__ out) {
  const int b = blockIdx.x;
  const int t = threadIdx.x;
  const float* xb = xyz + (size_t)b * NPTS * 3;
  // 128 KiB on purpose — occupancy fence (see header comment). Only [pp][0..7] used.
  __shared__ __align__(16) unsigned long long c_key[2][8192];
  FPS_REP32(FPS_DECL)
  FPS_REP32(FPS_INIT)
  float lx = xb[0], ly = xb[1], lz = xb[2];
  if (t == 0) {
    newxyz[(size_t)b * NM * 3 + 0] = lx;
    newxyz[(size_t)b * NM * 3 + 1] = ly;
    newxyz[(size_t)b * NM * 3 + 2] = lz;
    out[OUT_NEWXYZ + (size_t)b * NM * 3 + 0] = lx;
    out[OUT_NEWXYZ + (size_t)b * NM * 3 + 1] = ly;
    out[OUT_NEWXYZ + (size_t)b * NM * 3 + 2] = lz;
    out[OUT_IDX + b * NM] = 0.0f;
  }
  __syncthreads();
  const int wid = t >> 6;
  const unsigned kbase = 16383u - (unsigned)t;   // klo = 16383 - idx
  for (int s = 1; s < NM; ++s) {
    float best = -1.0f;
    unsigned klo = 0u;
    FPS_REP32(FPS_UPD)
    unsigned long long kr =
        ((unsigned long long)__float_as_uint(best) << 32) |
        (unsigned long long)klo;
#pragma unroll
    for (int off = 1; off < 64; off <<= 1) {
      unsigned long long ok = __shfl_xor(kr, off);
      kr = ok > kr ? ok : kr;
    }
    const int pp = s & 1;
    if ((t & 63) == 0) c_key[pp][wid] = kr;
    __syncthreads();
    // fold 8 wave candidates: broadcast LDS reads + in-register u64 max
    const ulonglong2* ck = reinterpret_cast<const ulonglong2*>(&c_key[pp][0]);
    ulonglong2 k01 = ck[0], k23 = ck[1], k45 = ck[2], k67 = ck[3];
    unsigned long long k =
        umax64(umax64(umax64(k01.x, k01.y), umax64(k23.x, k23.y)),
               umax64(umax64(k45.x, k45.y), umax64(k67.x, k67.y)));
    const int bi = 16383 - (int)(unsigned)(k & 0xffffffffull);
    // broadcast L2 load of the winner's coords (same addr across lanes)
    lx = xb[bi * 3 + 0];
    ly = xb[bi * 3 + 1];
    lz = xb[bi * 3 + 2];
    if (t == 0) {
      newxyz[((size_t)b * NM + s) * 3 + 0] = lx;
      newxyz[((size_t)b * NM + s) * 3 + 1] = ly;
      newxyz[((size_t)b * NM + s) * 3 + 2] = lz;
      out[OUT_NEWXYZ + ((size_t)b * NM + s) * 3 + 0] = lx;
      out[OUT_NEWXYZ + ((size_t)b * NM + s) * 3 + 1] = ly;
      out[OUT_NEWXYZ + ((size_t)b * NM + s) * 3 + 2] = lz;
      out[OUT_IDX + b * NM + s] = (float)bi;
    }
  }
}

// ---------------- ball query: first NK indices with d2<=r2, pad with first ----
// one wave per (b,m); also histogram counts + xyz partial sums for emb.
__global__ __launch_bounds__(256) void k_ball(const float* __restrict__ xyz,
                                              const float* __restrict__ newxyz,
                                              int* __restrict__ idxball,
                                              int* __restrict__ cnt,
                                              float* __restrict__ emb) {
  __shared__ int s_idx[4][NK];
  const int lane = threadIdx.x & 63, wid = threadIdx.x >> 6;
  const int gid = blockIdx.x * 4 + wid; // (b,m)
  const int b = gid >> 10;
  const float* xb = xyz + (size_t)b * NPTS * 3;
  const float cx = newxyz[gid * 3 + 0];
  const float cy = newxyz[gid * 3 + 1];
  const float cz = newxyz[gid * 3 + 2];
  int total = 0;
  for (int base = 0; base < NPTS && total < NK; base += 64) {
    int n = base + lane;
    float dx = __fsub_rn(xb[n * 3 + 0], cx);
    float dy = __fsub_rn(xb[n * 3 + 1], cy);
    float dz = __fsub_rn(xb[n * 3 + 2], cz);
    float d2 = __fadd_rn(__fadd_rn(__fmul_rn(dx, dx), __fmul_rn(dy, dy)),
                         __fmul_rn(dz, dz));
    bool hit = d2 <= RAD2;
    unsigned long long mask = __ballot(hit);
    int pos = total + (int)__popcll(mask & ((1ull << lane) - 1ull));
    if (hit && pos < NK) s_idx[wid][pos] = n;
    total += (int)__popcll(mask);
  }
  int tt = total < NK ? total : NK;
  if (lane >= tt && lane < NK) s_idx[wid][lane] = s_idx[wid][0];
  int v = 0;
  if (lane < NK) {
    v = s_idx[wid][lane];
    idxball[(size_t)gid * NK + lane] = v;
    atomicAdd(&cnt[b * NPTS + v], 1);
  }
  float sx = 0.f, sy = 0.f, sz = 0.f;
  if (lane < NK) { sx = xb[v * 3 + 0]; sy = xb[v * 3 + 1]; sz = xb[v * 3 + 2]; }
#pragma unroll
  for (int off = 1; off < 64; off <<= 1) {
    sx += __shfl_xor(sx, off);
    sy += __shfl_xor(sy, off);
    sz += __shfl_xor(sz, off);
  }
  if (lane == 0) {
    atomicAdd(&emb[b * 96 + 0], sx - 32.0f * cx);
    atomicAdd(&emb[b * 96 + 1], sy - 32.0f * cy);
    atomicAdd(&emb[b * 96 + 2], sz - 32.0f * cz);
  }
}

// ---------------- emb feature part: emb[b,3+c] = sum_n cnt[b,n]*feat[b,c,n] ----
__global__ __launch_bounds__(256) void k_embfeat(const float* __restrict__ feat,
                                                 const int* __restrict__ cnt,
                                                 float* __restrict__ emb) {
  const int c = blockIdx.x, b = blockIdx.y;
  const float* f = feat + ((size_t)b * NC + c) * NPTS;
  const int* ct = cnt + b * NPTS;
  float acc = 0.f;
  for (int n = threadIdx.x; n < NPTS; n += 256)
    acc = fmaf((float)ct[n], f[n], acc);
  __shared__ float red[4];
#pragma unroll
  for (int off = 1; off < 64; off <<= 1) acc += __shfl_xor(acc, off);
  if ((threadIdx.x & 63) == 0) red[threadIdx.x >> 6] = acc;
  __syncthreads();
  if (threadIdx.x == 0)
    emb[b * 96 + 3 + c] = red[0] + red[1] + red[2] + red[3];
}

// ---------------- pe: proj + layernorm + exact gelu ----------------
__global__ __launch_bounds__(64) void k_pe(const float* __restrict__ prompt,
                                           const float* __restrict__ projw,
                                           const float* __restrict__ projb,
                                           const float* __restrict__ lng,
                                           const float* __restrict__ lnb,
                                           float* __restrict__ pe) {
  const int m = blockIdx.x, lane = threadIdx.x;
  const float p0 = prompt[m * 2 + 0], p1 = prompt[m * 2 + 1];
  const int c1 = lane, c2 = lane + 64;
  float v1 = p0 * projw[c1 * 2 + 0] + p1 * projw[c1 * 2 + 1] + projb[c1];
  float v2 = 0.f;
  if (c2 < NCP) v2 = p0 * projw[c2 * 2 + 0] + p1 * projw[c2 * 2 + 1] + projb[c2];
  float s = v1 + ((c2 < NCP) ? v2 : 0.f);
#pragma unroll
  for (int off = 1; off < 64; off <<= 1) s += __shfl_xor(s, off);
  float mu = s * (1.0f / 67.0f);
  float d1 = v1 - mu;
  float d2v = (c2 < NCP) ? (v2 - mu) : 0.f;
  float q = d1 * d1 + d2v * d2v;
#pragma unroll
  for (int off = 1; off < 64; off <<= 1) q += __shfl_xor(q, off);
  float inv = 1.0f / sqrtf(q * (1.0f / 67.0f) + 1e-5f);
  {
    float y = d1 * inv * lng[c1] + lnb[c1];
    pe[m * NCP + c1] = 0.5f * y * (1.0f + erff(y * 0.70710678118654752f));
  }
  if (c2 < NCP) {
    float y = (v2 - mu) * inv * lng[c2] + lnb[c2];
    pe[m * NCP + c2] = 0.5f * y * (1.0f + erff(y * 0.70710678118654752f));
  }
}

// ---------------- pw: softmax(emb/32768 @ pw_w.T + pw_b) ----------------
__global__ __launch_bounds__(1024) void k_pw(const float* __restrict__ emb,
                                             const float* __restrict__ pww,
                                             const float* __restrict__ pwb,
                                             float* __restrict__ pw) {
  const int b = blockIdx.x, m = threadIdx.x;
  __shared__ float se[NCP];
  __shared__ float red[16];
  __shared__ float bcast;
  if (m < NCP) se[m] = emb[b * 96 + m] * (1.0f / 32768.0f);
  __syncthreads();
  float acc = pwb[m];
  for (int c = 0; c < NCP; ++c) acc = fmaf(se[c], pww[m * NCP + c], acc);
  float mx = acc;
#pragma unroll
  for (int off = 1; off < 64; off <<= 1) mx = fmaxf(mx, __shfl_xor(mx, off));
  if ((m & 63) == 0) red[m >> 6] = mx;
  __syncthreads();
  if (m == 0) {
    float v = red[0];
    for (int w = 1; w < 16; ++w) v = fmaxf(v, red[w]);
    bcast = v;
  }
  __syncthreads();
  float e = expf(acc - bcast);
  float ssum = e;
#pragma unroll
  for (int off = 1; off < 64; off <<= 1) ssum += __shfl_xor(ssum, off);
  if ((m & 63) == 0) red[m >> 6] = ssum;
  __syncthreads();
  if (m == 0) {
    float v = 0.f;
    for (int w = 0; w < 16; ++w) v += red[w];
    bcast = v;
  }
  __syncthreads();
  pw[b * NM + m] = e / bcast;
}

// ---------------- fused gather + pe*pw + conv0 + conv1 + maxpool ----------------
__global__ __launch_bounds__(256) void k_main(const float* __restrict__ feat,
                                              const float* __restrict__ xyz,
                                              const float* __restrict__ newxyz,
                                              const int* __restrict__ idxball,
                                              const float* __restrict__ pe,
                                              const float* __restrict__ pwbuf,
                                              const float* __restrict__ w0t,
                                              const float* __restrict__ b0,
                                              const float* __restrict__ w1t,
                                              const float* __restrict__ b1,
                                              float* __restrict__ out) {
  __shared__ __align__(16) float g[NCP * 36];
  __shared__ __align__(16) float h0[128 * 36];
  __shared__ int s_idx[NK];
  __shared__ float spe[NCP];
  const int bid = blockIdx.x;
  const int b = bid >> 10, m = bid & 1023;
  const int t = threadIdx.x;
  const float pwv = pwbuf[bid];
  if (t < NK) {
    int n = idxball[(size_t)bid * NK + t];
    n = n < 0 ? 0 : (n > NPTS - 1 ? NPTS - 1 : n); // insurance clamp
    s_idx[t] = n;
  }
  if (t < NCP) spe[t] = pe[m * NCP + t] * pwv;
  __syncthreads();
  // stage feature rows of g (gather from native (B,C,N) layout; L3-resident)
  for (int e = t; e < NK * NC; e += 256) {
    int k = e >> 6, c = e & 63;
    int n = s_idx[k];
    g[(3 + c) * 36 + k] = feat[((size_t)b * NC + c) * NPTS + n] + spe[3 + c];
  }
  // stage xyz rows of g
  if (t < 96) {
    int k = t & 31, d = t >> 5;
    int n = s_idx[k];
    float cv = newxyz[bid * 3 + d];
    g[d * 36 + k] = (xyz[((size_t)b * NPTS + n) * 3 + d] - cv) + spe[d];
  }
  __syncthreads();
  // layer0: h0[o][k] = relu(sum_c W0[o,c]*g[c,k] + b0[o])
  {
    const int o = t & 127, kb = (t >> 7) * 16;
    float acc[16];
    float bb = b0[o];
#pragma unroll
    for (int j = 0; j < 16; ++j) acc[j] = bb;
    for (int c = 0; c < NCP; ++c) {
      float w = w0t[c * 128 + o];
      const float4* gp = reinterpret_cast<const float4*>(&g[c * 36 + kb]);
#pragma unroll
      for (int qq = 0; qq < 4; ++qq) {
        float4 gv = gp[qq];
        acc[qq * 4 + 0] = fmaf(w, gv.x, acc[qq * 4 + 0]);
        acc[qq * 4 + 1] = fmaf(w, gv.y, acc[qq * 4 + 1]);
        acc[qq * 4 + 2] = fmaf(w, gv.z, acc[qq * 4 + 2]);
        acc[qq * 4 + 3] = fmaf(w, gv.w, acc[qq * 4 + 3]);
      }
    }
    float4* hp = reinterpret_cast<float4*>(&h0[o * 36 + kb]);
#pragma unroll
    for (int qq = 0; qq < 4; ++qq) {
      float4 hv;
      hv.x = fmaxf(acc[qq * 4 + 0], 0.f);
      hv.y = fmaxf(acc[qq * 4 + 1], 0.f);
      hv.z = fmaxf(acc[qq * 4 + 2], 0.f);
      hv.w = fmaxf(acc[qq * 4 + 3], 0.f);
      hp[qq] = hv;
    }
  }
  __syncthreads();
  // layer1: pooled[o2] = max_k relu(sum_o W1[o2,o]*h0[o,k] + b1[o2])
  {
    const int o2 = t;
    float acc[32];
    float bb = b1[o2];
#pragma unroll
    for (int j = 0; j < 32; ++j) acc[j] = bb;
    for (int o = 0; o < 128; ++o) {
      float w = w1t[o * 256 + o2];
      const float4* hp = reinterpret_cast<const float4*>(&h0[o * 36]);
#pragma unroll
      for (int qq = 0; qq < 8; ++qq) {
        float4 hv = hp[qq];
        acc[qq * 4 + 0] = fmaf(w, hv.x, acc[qq * 4 + 0]);
        acc[qq * 4 + 1] = fmaf(w, hv.y, acc[qq * 4 + 1]);
        acc[qq * 4 + 2] = fmaf(w, hv.z, acc[qq * 4 + 2]);
        acc[qq * 4 + 3] = fmaf(w, hv.w, acc[qq * 4 + 3]);
      }
    }
    float mx = 0.f; // relu floor
#pragma unroll
    for (int k = 0; k < 32; ++k) mx = fmaxf(mx, acc[k]);
    out[OUT_POOLED + ((size_t)(b * 256 + o2)) * NM + m] = mx;
  }
}

extern "C" void kernel_launch(void* const* d_in, const int* in_sizes, int n_in,
                              void* d_out, int out_size, void* d_ws, size_t ws_size,
                              hipStream_t stream) {
  const float* xyz    = (const float*)d_in[0];
  const float* feat   = (const float*)d_in[1];
  const float* prompt = (const float*)d_in[2];
  const float* projw  = (const float*)d_in[3];
  const float* projb  = (const float*)d_in[4];
  const float* lng    = (const float*)d_in[5];
  const float* lnb    = (const float*)d_in[6];
  const float* pww    = (const float*)d_in[7];
  const float* pwb    = (const float*)d_in[8];
  const float* w0     = (const float*)d_in[9];
  const float* b0     = (const float*)d_in[10];
  const float* w1     = (const float*)d_in[11];
  const float* b1     = (const float*)d_in[12];
  float* ws = (float*)d_ws;
  float* out = (float*)d_out;

  float* w0t     = ws + OFF_W0T;
  float* w1t     = ws + OFF_W1T;
  float* nxyz    = ws + OFF_NEWXYZ;
  int*   idxball = (int*)(ws + OFF_IDXBALL);
  int*   cnt     = (int*)(ws + OFF_CNT);
  float* emb     = ws + OFF_EMB;
  float* pwv     = ws + OFF_PW;
  float* pev     = ws + OFF_PE;

  hipMemsetAsync(cnt, 0, NB * NPTS * sizeof(int), stream);
  hipMemsetAsync(emb, 0, NB * 96 * sizeof(float), stream);

  k_prepw<<<128, 256, 0, stream>>>(w0, w1, w0t, w1t);
  k_fps<<<NB, 512, 0, stream>>>(xyz, nxyz, out);
  k_ball<<<NB * NM / 4, 256, 0, stream>>>(xyz, nxyz, idxball, cnt, emb);
  k_embfeat<<<dim3(NC, NB), 256, 0, stream>>>(feat, cnt, emb);
  k_pe<<<NM, 64, 0, stream>>>(prompt, projw, projb, lng, lnb, pev);
  k_pw<<<NB, 1024, 0, stream>>>(emb, pww, pwb, pwv);
  k_main<<<NB * NM, 256, 0, stream>>>(feat, xyz, nxyz, idxball, pev, pwv,
                                      w0t, b0, w1t, b1, out);
}